// Round 1
// baseline (192.160 us; speedup 1.0000x reference)
//
#include <hip/hip_runtime.h>
#include <math.h>

#define B_TOT 2048
#define R_TOT 512
#define D_TOT 256
#define LOG2E 1.4426950408889634f
#define XS_STRIDE 65   // 64 + 1 pad: conflict-free lane-consecutive reads

// ---------------------------------------------------------------------------
// Kernel 1: precompute per-(r,d) parameters into workspace, packed float4:
//   A  = -log2(e) * kappa * tanh(sign_param)
//   Bc = -A * th
//   m1 = 1 - sigmoid(mask_logit)
// so that  e = exp2(A*x + Bc)  and  gated = (1 + m1*e) / (1 + e).
// ---------------------------------------------------------------------------
__global__ void prep_kernel(const float* __restrict__ th,
                            const float* __restrict__ sign_param,
                            const float* __restrict__ mask_logit,
                            const float* __restrict__ log_kappa,
                            float4* __restrict__ pp) {
    int idx = blockIdx.x * blockDim.x + threadIdx.x;   // idx = r*D + d
    if (idx >= R_TOT * D_TOT) return;
    float kappa = expf(log_kappa[0]);
    float c  = kappa * tanhf(sign_param[idx]);
    float A  = -LOG2E * c;
    float Bc = -A * th[idx];
    float m  = 1.0f / (1.0f + expf(-mask_logit[idx]));
    pp[idx] = make_float4(A, Bc, 1.0f - m, 0.0f);
}

// ---------------------------------------------------------------------------
// Kernel 2: main. WG = 256 threads = 4 waves. Each WG: 64 batches x 32 rules.
// lane <-> batch; each wave owns 8 rule-chains; product over d in chunks of 4
// with one v_rcp per chunk (num/den split; provably no overflow).
// grid = (16 rule-groups, 32 batch-groups) = 512 WGs = 2/CU.
// ---------------------------------------------------------------------------
__global__ __launch_bounds__(256, 2) void main_kernel(
        const float*  __restrict__ x,       // [B_TOT][D_TOT]
        const float4* __restrict__ pp,      // [R_TOT][D_TOT]
        const float*  __restrict__ head_w,  // [R_TOT]
        float*        __restrict__ part) {  // [16][B_TOT]
    __shared__ float xs[D_TOT * XS_STRIDE];   // x transposed: xs[d*65 + b]
    __shared__ float red[256];

    const int tid  = threadIdx.x;
    const int lane = tid & 63;
    const int wave = tid >> 6;
    const int rg   = blockIdx.x;       // 0..15
    const int bg   = blockIdx.y;       // 0..31
    const int b0   = bg << 6;

    // Stage x[b0..b0+63][:] -> LDS, transposed. Coalesced float4 global reads.
    const float4* x4 = (const float4*)(x + (size_t)b0 * D_TOT);
    #pragma unroll
    for (int it = 0; it < 16; it++) {
        int i  = tid + it * 256;       // 0..4095
        int b  = i >> 6;               // wave-uniform
        int dq = i & 63;               // = lane
        float4 v = x4[b * (D_TOT / 4) + dq];
        int d4 = dq << 2;
        xs[(d4 + 0) * XS_STRIDE + b] = v.x;
        xs[(d4 + 1) * XS_STRIDE + b] = v.y;
        xs[(d4 + 2) * XS_STRIDE + b] = v.z;
        xs[(d4 + 3) * XS_STRIDE + b] = v.w;
    }
    __syncthreads();

    const int rbase = (rg << 5) + (wave << 3);
    const float4* prow = pp + (size_t)rbase * D_TOT;

    float acc[8];
    #pragma unroll
    for (int j = 0; j < 8; j++) acc[j] = 1.0f;

    for (int dc = 0; dc < D_TOT; dc += 4) {
        // x values for this lane's batch, 4 d's (broadcast-free, 2 lanes/bank)
        float xv0 = xs[(dc + 0) * XS_STRIDE + lane];
        float xv1 = xs[(dc + 1) * XS_STRIDE + lane];
        float xv2 = xs[(dc + 2) * XS_STRIDE + lane];
        float xv3 = xs[(dc + 3) * XS_STRIDE + lane];
        #pragma unroll
        for (int j = 0; j < 8; j++) {
            const float4* p = prow + j * D_TOT + dc;  // wave-uniform addr
            float4 p0 = p[0], p1 = p[1], p2 = p[2], p3 = p[3];
            float e0 = __builtin_amdgcn_exp2f(fmaf(p0.x, xv0, p0.y));
            float e1 = __builtin_amdgcn_exp2f(fmaf(p1.x, xv1, p1.y));
            float e2 = __builtin_amdgcn_exp2f(fmaf(p2.x, xv2, p2.y));
            float e3 = __builtin_amdgcn_exp2f(fmaf(p3.x, xv3, p3.y));
            float n0 = fmaf(p0.z, e0, 1.0f);
            float n1 = fmaf(p1.z, e1, 1.0f);
            float n2 = fmaf(p2.z, e2, 1.0f);
            float n3 = fmaf(p3.z, e3, 1.0f);
            float num = (n0 * n1) * (n2 * n3);
            float den = ((1.0f + e0) * (1.0f + e1)) * ((1.0f + e2) * (1.0f + e3));
            acc[j] *= num * __builtin_amdgcn_rcpf(den);
        }
    }

    // partial = sum_j w[rbase+j] * z_j  for this lane's batch
    float partial = 0.0f;
    #pragma unroll
    for (int j = 0; j < 8; j++)
        partial = fmaf(head_w[rbase + j], acc[j], partial);

    red[tid] = partial;
    __syncthreads();
    if (wave == 0) {
        float t = red[lane] + red[64 + lane] + red[128 + lane] + red[192 + lane];
        part[rg * B_TOT + b0 + lane] = t;
    }
}

// ---------------------------------------------------------------------------
// Kernel 3: deterministic final reduction over the 16 rule-groups + bias.
// ---------------------------------------------------------------------------
__global__ void reduce_kernel(const float* __restrict__ part,
                              const float* __restrict__ head_b,
                              float* __restrict__ y) {
    int b = blockIdx.x * blockDim.x + threadIdx.x;
    if (b >= B_TOT) return;
    float s = head_b[0];
    #pragma unroll
    for (int g = 0; g < 16; g++) s += part[g * B_TOT + b];
    y[b] = s;
}

extern "C" void kernel_launch(void* const* d_in, const int* in_sizes, int n_in,
                              void* d_out, int out_size, void* d_ws, size_t ws_size,
                              hipStream_t stream) {
    const float* x  = (const float*)d_in[0];
    const float* th = (const float*)d_in[1];
    const float* sp = (const float*)d_in[2];
    const float* ml = (const float*)d_in[3];
    const float* lk = (const float*)d_in[4];
    const float* hw = (const float*)d_in[5];
    const float* hb = (const float*)d_in[6];
    float* y = (float*)d_out;

    float4* pp  = (float4*)d_ws;                                   // 2 MB
    float* part = (float*)((char*)d_ws +
                           (size_t)R_TOT * D_TOT * sizeof(float4)); // 128 KB

    prep_kernel<<<(R_TOT * D_TOT + 255) / 256, 256, 0, stream>>>(th, sp, ml, lk, pp);
    dim3 grid(16, 32, 1);
    main_kernel<<<grid, 256, 0, stream>>>(x, pp, hw, part);
    reduce_kernel<<<(B_TOT + 255) / 256, 256, 0, stream>>>(part, hb, y);
}

// Round 2
// 129.392 us; speedup vs baseline: 1.4851x; 1.4851x over previous
//
#include <hip/hip_runtime.h>
#include <math.h>

#define B_TOT 2048
#define R_TOT 512
#define D_TOT 256
#define LOG2E 1.4426950408889634f

#define D_TILE 64
#define N_TILES (D_TOT / D_TILE)          // 4
#define RULES_PER_WG 16                   // 4 waves x 4 rules
#define RULES_PER_WAVE 4
#define N_RG (R_TOT / RULES_PER_WG)       // 32
#define N_BG (B_TOT / 64)                 // 32

// ---------------------------------------------------------------------------
// Single fused kernel. WG = 256 threads = 4 waves; 64 batches x 16 rules.
// Per d-tile (64 d's):
//   - stage x[64b x 64d] transposed+swizzled into LDS (conflict-free reads)
//   - compute per-(r,d) params (A, Bc, m1) for 16 rules into LDS
//   - product loop: chunks of 4 d, one v_rcp per chunk, params via LDS
//     wave-uniform broadcast reads
// Epilogue: head dot over 4 rules/wave, cross-wave LDS reduce, atomicAdd to y.
//   gated = (1 + m1*e) / (1 + e),  e = exp2(A*x + Bc)
//   A = -log2e * kappa * tanh(sign),  Bc = -A*th,  m1 = 1 - sigmoid(mask)
// ---------------------------------------------------------------------------
__global__ __launch_bounds__(256, 4) void main_kernel(
        const float* __restrict__ x,       // [B_TOT][D_TOT]
        const float* __restrict__ th,      // [R_TOT][D_TOT]
        const float* __restrict__ sp,      // [R_TOT][D_TOT]
        const float* __restrict__ ml,      // [R_TOT][D_TOT]
        const float* __restrict__ lk,      // [1]
        const float* __restrict__ head_w,  // [R_TOT]
        const float* __restrict__ head_b,  // [1]
        float*       __restrict__ y) {     // [B_TOT]
    __shared__ float xs[D_TILE * 64];          // [d][b ^ swz(d)]   16 KB
    __shared__ float pA[RULES_PER_WG * D_TILE]; // 4 KB
    __shared__ float pB[RULES_PER_WG * D_TILE]; // 4 KB
    __shared__ float pM[RULES_PER_WG * D_TILE]; // 4 KB
    __shared__ float red[256];                  // 1 KB

    const int tid  = threadIdx.x;
    const int lane = tid & 63;
    const int wave = tid >> 6;
    const int rg   = blockIdx.x;         // 0..31
    const int bg   = blockIdx.y;         // 0..31
    const int b0   = bg << 6;
    const int rbase = rg * RULES_PER_WG;

    // kappa = exp(log_kappa); kmul = -log2e * kappa  (uniform, L1 broadcast)
    const float kmul = -LOG2E * __builtin_amdgcn_exp2f(lk[0] * LOG2E);

    float acc[RULES_PER_WAVE];
    #pragma unroll
    for (int j = 0; j < RULES_PER_WAVE; j++) acc[j] = 1.0f;

    const float4* x4 = (const float4*)x;

    for (int dt = 0; dt < N_TILES; dt++) {
        const int dg0 = dt * D_TILE;
        if (dt) __syncthreads();   // protect LDS reuse from previous tile

        // ---- stage x tile: 64 b x 64 d, transposed with XOR swizzle ----
        #pragma unroll
        for (int it = 0; it < 4; it++) {
            int i  = it * 256 + tid;          // 0..1023
            int b  = i >> 4;                  // 0..63
            int fq = i & 15;                  // float4 index within tile row
            float4 v = x4[(size_t)(b0 + b) * (D_TOT / 4) + dt * 16 + fq];
            int d0  = fq << 2;
            int col = b ^ (fq & 15);          // swz(d) = (d>>2)&15
            xs[(d0 + 0) * 64 + col] = v.x;
            xs[(d0 + 1) * 64 + col] = v.y;
            xs[(d0 + 2) * 64 + col] = v.z;
            xs[(d0 + 3) * 64 + col] = v.w;
        }

        // ---- stage params: 16 r x 64 d ----
        #pragma unroll
        for (int it = 0; it < 4; it++) {
            int i  = it * 256 + tid;          // 0..1023
            int rl = i >> 6;                  // 0..15
            int dl = i & 63;                  // 0..63
            size_t g = (size_t)(rbase + rl) * D_TOT + dg0 + dl;
            float u  = sp[g];
            // tanh(u) = 1 - 2/(exp2(2*log2e*u)+1)
            float eu = __builtin_amdgcn_exp2f(2.0f * LOG2E * u);
            float t  = 1.0f - 2.0f * __builtin_amdgcn_rcpf(eu + 1.0f);
            float A  = kmul * t;
            float Bc = -A * th[g];
            // m1 = 1 - sigmoid(ml) = 1/(1+exp(ml))
            float em = __builtin_amdgcn_exp2f(LOG2E * ml[g]);
            float m1 = __builtin_amdgcn_rcpf(1.0f + em);
            pA[rl * D_TILE + dl] = A;
            pB[rl * D_TILE + dl] = Bc;
            pM[rl * D_TILE + dl] = m1;
        }
        __syncthreads();

        // ---- product over this tile's 64 d, chunks of 4 ----
        #pragma unroll 2
        for (int dc = 0; dc < D_TILE; dc += 4) {
            int col = lane ^ ((dc >> 2) & 15);
            int xb  = dc * 64 + col;
            float xv0 = xs[xb];
            float xv1 = xs[xb + 64];
            float xv2 = xs[xb + 128];
            float xv3 = xs[xb + 192];
            #pragma unroll
            for (int j = 0; j < RULES_PER_WAVE; j++) {
                int pb = (wave * RULES_PER_WAVE + j) * D_TILE + dc;
                float4 a4 = *(const float4*)&pA[pb];   // wave-uniform broadcast
                float4 b4 = *(const float4*)&pB[pb];
                float4 m4 = *(const float4*)&pM[pb];
                float e0 = __builtin_amdgcn_exp2f(fmaf(a4.x, xv0, b4.x));
                float e1 = __builtin_amdgcn_exp2f(fmaf(a4.y, xv1, b4.y));
                float e2 = __builtin_amdgcn_exp2f(fmaf(a4.z, xv2, b4.z));
                float e3 = __builtin_amdgcn_exp2f(fmaf(a4.w, xv3, b4.w));
                float n0 = fmaf(m4.x, e0, 1.0f);
                float n1 = fmaf(m4.y, e1, 1.0f);
                float n2 = fmaf(m4.z, e2, 1.0f);
                float n3 = fmaf(m4.w, e3, 1.0f);
                float num = (n0 * n1) * (n2 * n3);
                float den = ((1.0f + e0) * (1.0f + e1)) *
                            ((1.0f + e2) * (1.0f + e3));
                acc[j] *= num * __builtin_amdgcn_rcpf(den);
            }
        }
    }

    // ---- head: partial = sum_j w[r]*z_j for this lane's batch ----
    float partial = 0.0f;
    #pragma unroll
    for (int j = 0; j < RULES_PER_WAVE; j++)
        partial = fmaf(head_w[rbase + wave * RULES_PER_WAVE + j], acc[j], partial);

    __syncthreads();          // red[] aliases nothing, but order vs tile loop
    red[tid] = partial;
    __syncthreads();
    if (wave == 0) {
        float t = red[lane] + red[64 + lane] + red[128 + lane] + red[192 + lane];
        if (rg == 0) t += head_b[0];        // bias added exactly once per batch
        atomicAdd(&y[b0 + lane], t);
    }
}

extern "C" void kernel_launch(void* const* d_in, const int* in_sizes, int n_in,
                              void* d_out, int out_size, void* d_ws, size_t ws_size,
                              hipStream_t stream) {
    const float* x  = (const float*)d_in[0];
    const float* th = (const float*)d_in[1];
    const float* sp = (const float*)d_in[2];
    const float* ml = (const float*)d_in[3];
    const float* lk = (const float*)d_in[4];
    const float* hw = (const float*)d_in[5];
    const float* hb = (const float*)d_in[6];
    float* y = (float*)d_out;

    hipMemsetAsync(y, 0, (size_t)out_size * sizeof(float), stream);
    dim3 grid(N_RG, N_BG, 1);
    main_kernel<<<grid, 256, 0, stream>>>(x, th, sp, ml, lk, hw, hb, y);
}

// Round 3
// 127.017 us; speedup vs baseline: 1.5129x; 1.0187x over previous
//
#include <hip/hip_runtime.h>
#include <math.h>

#define B_TOT 2048
#define R_TOT 512
#define D_TOT 256
#define LOG2E 1.4426950408889634f

#define D_TILE 64
#define N_TILES (D_TOT / D_TILE)      // 4
#define RULES_PER_WG 8                // 4 waves x 2 rules
#define RULES_PER_WAVE 2
#define N_RG (R_TOT / RULES_PER_WG)   // 64
#define N_BG (B_TOT / 64)             // 32

// pp layout: [R][64 chunks][12] = {A0..3, Bc0..3, m1_0..3} per 4-d chunk.
// 48 B per chunk, 16B-aligned -> three s_load_dwordx4 per (rule, chunk).

// ---------------------------------------------------------------------------
// Prep: per-(r,d) params once (they were being recomputed 32x in round 2).
//   A = -log2e * kappa * tanh(sign), Bc = -A*th, m1 = 1 - sigmoid(mask)
//   gated = (1 + m1*e)/(1 + e), e = exp2(A*x + Bc)
// ---------------------------------------------------------------------------
__global__ void prep_kernel(const float* __restrict__ th,
                            const float* __restrict__ sp,
                            const float* __restrict__ ml,
                            const float* __restrict__ lk,
                            float* __restrict__ pp) {
    int idx = blockIdx.x * 256 + threadIdx.x;   // r*256 + d
    if (idx >= R_TOT * D_TOT) return;
    float kmul = -LOG2E * __builtin_amdgcn_exp2f(lk[0] * LOG2E);
    float u  = sp[idx];
    float eu = __builtin_amdgcn_exp2f(2.0f * LOG2E * u);
    float t  = 1.0f - 2.0f * __builtin_amdgcn_rcpf(eu + 1.0f);
    float A  = kmul * t;
    float Bc = -A * th[idx];
    float em = __builtin_amdgcn_exp2f(LOG2E * ml[idx]);
    float m1 = __builtin_amdgcn_rcpf(1.0f + em);
    int r = idx >> 8, d = idx & 255;
    int q = d >> 2, j = d & 3;
    float* base = pp + ((size_t)r * 64 + q) * 12;
    base[j]     = A;
    base[4 + j] = Bc;
    base[8 + j] = m1;
}

// ---------------------------------------------------------------------------
// Main: WG = 256 thr = 4 waves; 64 batches x 8 rules; grid 64x32 = 2048 WGs
// = exactly 8 WGs/CU = 32 waves/CU (LDS 17.25 KB, VGPR<=64). Params come in
// through the scalar pipe (uniform address via readfirstlane -> s_load).
// ---------------------------------------------------------------------------
__global__ __launch_bounds__(256, 8) void main_kernel(
        const float* __restrict__ x,       // [B_TOT][D_TOT]
        const float* __restrict__ pp,      // [R_TOT][64][12]
        const float* __restrict__ head_w,  // [R_TOT]
        const float* __restrict__ head_b,  // [1]
        float*       __restrict__ y) {     // [B_TOT]
    __shared__ float xs[D_TILE * 64];      // transposed+swizzled x tile, 16 KB
    __shared__ float red[256];

    const int tid  = threadIdx.x;
    const int lane = tid & 63;
    const int wave = __builtin_amdgcn_readfirstlane(tid >> 6);  // force SGPR
    const int rg   = blockIdx.x;          // 0..63
    const int bg   = blockIdx.y;          // 0..31
    const int b0   = bg << 6;
    const int r0   = rg * RULES_PER_WG + wave * RULES_PER_WAVE; // uniform

    float acc0 = 1.0f, acc1 = 1.0f;
    const float4* x4 = (const float4*)x;

    for (int dt = 0; dt < N_TILES; dt++) {
        if (dt) __syncthreads();
        // ---- stage x tile: 64 b x 64 d, transposed, XOR-swizzled ----
        #pragma unroll
        for (int it = 0; it < 4; it++) {
            int i  = it * 256 + tid;      // 0..1023
            int b  = i >> 4;              // 0..63
            int fq = i & 15;              // float4 col within tile
            float4 v = x4[(size_t)(b0 + b) * (D_TOT / 4) + dt * 16 + fq];
            int d0  = fq << 2;
            int col = b ^ fq;
            xs[(d0 + 0) * 64 + col] = v.x;
            xs[(d0 + 1) * 64 + col] = v.y;
            xs[(d0 + 2) * 64 + col] = v.z;
            xs[(d0 + 3) * 64 + col] = v.w;
        }
        __syncthreads();

        const float* P0 = pp + ((size_t)r0 * 64 + dt * 16) * 12;  // uniform
        const float* P1 = P0 + 64 * 12;                           // rule r0+1

        #pragma unroll 2
        for (int c = 0; c < 16; c++) {
            int col = lane ^ c;
            int xb  = (c << 2) * 64 + col;
            float xv0 = xs[xb];
            float xv1 = xs[xb + 64];
            float xv2 = xs[xb + 128];
            float xv3 = xs[xb + 192];

            const float4* q0 = (const float4*)(P0 + c * 12);
            const float4* q1 = (const float4*)(P1 + c * 12);
            float4 A0 = q0[0], Bq0 = q0[1], M0 = q0[2];   // s_load_dwordx4 x3
            float4 A1 = q1[0], Bq1 = q1[1], M1 = q1[2];

            {   // rule 0
                float e0 = __builtin_amdgcn_exp2f(fmaf(A0.x, xv0, Bq0.x));
                float e1 = __builtin_amdgcn_exp2f(fmaf(A0.y, xv1, Bq0.y));
                float e2 = __builtin_amdgcn_exp2f(fmaf(A0.z, xv2, Bq0.z));
                float e3 = __builtin_amdgcn_exp2f(fmaf(A0.w, xv3, Bq0.w));
                float n0 = fmaf(M0.x, e0, 1.0f);
                float n1 = fmaf(M0.y, e1, 1.0f);
                float n2 = fmaf(M0.z, e2, 1.0f);
                float n3 = fmaf(M0.w, e3, 1.0f);
                float num = (n0 * n1) * (n2 * n3);
                float den = ((1.0f + e0) * (1.0f + e1)) *
                            ((1.0f + e2) * (1.0f + e3));
                acc0 *= num * __builtin_amdgcn_rcpf(den);
            }
            {   // rule 1
                float e0 = __builtin_amdgcn_exp2f(fmaf(A1.x, xv0, Bq1.x));
                float e1 = __builtin_amdgcn_exp2f(fmaf(A1.y, xv1, Bq1.y));
                float e2 = __builtin_amdgcn_exp2f(fmaf(A1.z, xv2, Bq1.z));
                float e3 = __builtin_amdgcn_exp2f(fmaf(A1.w, xv3, Bq1.w));
                float n0 = fmaf(M1.x, e0, 1.0f);
                float n1 = fmaf(M1.y, e1, 1.0f);
                float n2 = fmaf(M1.z, e2, 1.0f);
                float n3 = fmaf(M1.w, e3, 1.0f);
                float num = (n0 * n1) * (n2 * n3);
                float den = ((1.0f + e0) * (1.0f + e1)) *
                            ((1.0f + e2) * (1.0f + e3));
                acc1 *= num * __builtin_amdgcn_rcpf(den);
            }
        }
    }

    // ---- head dot (2 rules/wave), cross-wave reduce, atomic combine ----
    float partial = fmaf(head_w[r0], acc0, head_w[r0 + 1] * acc1);
    red[tid] = partial;
    __syncthreads();
    if (wave == 0) {
        float t = red[lane] + red[64 + lane] + red[128 + lane] + red[192 + lane];
        if (rg == 0) t += head_b[0];       // bias exactly once per batch
        atomicAdd(&y[b0 + lane], t);
    }
}

extern "C" void kernel_launch(void* const* d_in, const int* in_sizes, int n_in,
                              void* d_out, int out_size, void* d_ws, size_t ws_size,
                              hipStream_t stream) {
    const float* x  = (const float*)d_in[0];
    const float* th = (const float*)d_in[1];
    const float* sp = (const float*)d_in[2];
    const float* ml = (const float*)d_in[3];
    const float* lk = (const float*)d_in[4];
    const float* hw = (const float*)d_in[5];
    const float* hb = (const float*)d_in[6];
    float* y = (float*)d_out;

    float* pp = (float*)d_ws;   // 512*64*12 floats = 1.5 MB

    hipMemsetAsync(y, 0, (size_t)out_size * sizeof(float), stream);
    prep_kernel<<<(R_TOT * D_TOT + 255) / 256, 256, 0, stream>>>(th, sp, ml, lk, pp);
    dim3 grid(N_RG, N_BG, 1);
    main_kernel<<<grid, 256, 0, stream>>>(x, pp, hw, hb, y);
}